// Round 10
// baseline (1531.393 us; speedup 1.0000x reference)
//
#include <hip/hip_runtime.h>
#include <hip/hip_bf16.h>

#define NS 512     // states
#define MS 256     // symbols
#define TB 256     // sequence length
#define NWG 16     // workgroups = batch groups
#define BPG 16     // batches per group
#define NA 60      // T cells pinned in AGPRs per wave
#define NV 37      // T cells pinned in arch VGPRs per wave
#define NLDS 31    // T cells in LDS per wave  (60+37+31 = 128 = all)

// workspace byte offsets
#define OFF_EEXP  0u          // f32 [256 sym][512 state] = 512KB
#define OFF_PEXP  524288u     // f32 [512]
#define OFF_TFRAG 526336u     // bf16 fragment-major [32 st][16 kb][64 lane][8] = 512KB

typedef __attribute__((ext_vector_type(8))) short short8;
typedef __attribute__((ext_vector_type(4))) float f32x4;

__device__ __forceinline__ unsigned short bf_bits(float f) {
    __hip_bfloat16 h = __float2bfloat16(f);
    unsigned short u; __builtin_memcpy(&u, &h, 2); return u;
}

__global__ void k_emission(const float* __restrict__ E, float* __restrict__ expET) {
    int n = blockIdx.x;
    int lane = threadIdx.x;
    const float* row = E + (size_t)n * MS;
    float v[4]; float mx = -1e30f;
#pragma unroll
    for (int j = 0; j < 4; ++j) { v[j] = row[lane + 64 * j]; mx = fmaxf(mx, v[j]); }
#pragma unroll
    for (int off = 1; off < 64; off <<= 1) mx = fmaxf(mx, __shfl_xor(mx, off));
    float s = 0.f;
#pragma unroll
    for (int j = 0; j < 4; ++j) s += __expf(v[j] - mx);
#pragma unroll
    for (int off = 1; off < 64; off <<= 1) s += __shfl_xor(s, off);
    float lse = mx + __logf(s);
#pragma unroll
    for (int j = 0; j < 4; ++j)
        expET[(size_t)(lane + 64 * j) * NS + n] = __expf(v[j] - lse);
}

// T fragments, MFMA-lane-major: cell (st,kb) holds T[state=st*16+li][k=kb*32+hk*8+j]
// at byte ((st*16+kb)<<10) + (hk*16+li)*16 + j*2.  Column-softmax over i (dim 0).
__global__ void k_transition(const float* __restrict__ U, __hip_bfloat16* __restrict__ Tf) {
    int k = blockIdx.x;
    int lane = threadIdx.x;
    float v[8]; float mx = -1e30f;
#pragma unroll
    for (int j = 0; j < 8; ++j) { v[j] = U[(size_t)(lane + 64 * j) * NS + k]; mx = fmaxf(mx, v[j]); }
#pragma unroll
    for (int off = 1; off < 64; off <<= 1) mx = fmaxf(mx, __shfl_xor(mx, off));
    float s = 0.f;
#pragma unroll
    for (int j = 0; j < 8; ++j) s += __expf(v[j] - mx);
#pragma unroll
    for (int off = 1; off < 64; off <<= 1) s += __shfl_xor(s, off);
    float lse = mx + __logf(s);
    int kb = k >> 5, hk = (k >> 3) & 3, jj = k & 7;
#pragma unroll
    for (int j = 0; j < 8; ++j) {
        int i = lane + 64 * j;
        int st = i >> 4, li = i & 15;
        size_t byte = ((size_t)(st * 16 + kb) << 10) + (unsigned)(hk * 16 + li) * 16 + jj * 2;
        *reinterpret_cast<unsigned short*>(reinterpret_cast<char*>(Tf) + byte) =
            bf_bits(__expf(v[j] - lse));
    }
}

__global__ void k_priors(const float* __restrict__ U, float* __restrict__ pexp) {
    int lane = threadIdx.x;
    float v[8]; float mx = -1e30f;
#pragma unroll
    for (int j = 0; j < 8; ++j) { v[j] = U[lane + 64 * j]; mx = fmaxf(mx, v[j]); }
#pragma unroll
    for (int off = 1; off < 64; off <<= 1) mx = fmaxf(mx, __shfl_xor(mx, off));
    float s = 0.f;
#pragma unroll
    for (int j = 0; j < 8; ++j) s += __expf(v[j] - mx);
#pragma unroll
    for (int off = 1; off < 64; off <<= 1) s += __shfl_xor(s, off);
    float lse = mx + __logf(s);
#pragma unroll
    for (int j = 0; j < 8; ++j) pexp[lane + 64 * j] = __expf(v[j] - lse);
}

// 16 WGs x 256 threads (4 waves, 1 wave/SIMD -> 512-reg budget). WG owns 16
// batches + all 512 states. Wave w owns states [w*128,(w+1)*128) = 128 T-cells:
// 60 in AGPRs + 37 in arch VGPRs (asm class-pinned) + 31 in LDS. T is fully
// CU-resident: zero global T traffic in the scan. alpha double-buffered in
// LDS; deferred normalization (rowsum(P_raw(t)) = q(t-1), T cols sum to 1);
// one barrier per step; out[b,t] = running sum of log q.
__launch_bounds__(256, 1)
__global__ void k_forward(const int* __restrict__ batch, const float* __restrict__ expET,
                          const __hip_bfloat16* __restrict__ Tf,
                          const float* __restrict__ pexp,
                          float* __restrict__ out) {
    __shared__ __align__(16) char Alds[2][16 * 1024];    // 32KB: A frags per kb
    __shared__ __align__(16) char Tlds[4][NLDS * 1024];  // 124KB: cells 97..127 per wave
    __shared__ __align__(16) float qred[2][BPG][4];      // 512B: [par][batch][wave]

    const int tid = threadIdx.x;
    const int lane = tid & 63;
    const int w = tid >> 6;       // wave 0..3 -> states [w*128,(w+1)*128)
    const int hi = lane >> 4;
    const int lo = lane & 15;
    const int g = blockIdx.x;
    const int b0 = g * BPG;
    const char* TfC = reinterpret_cast<const char*>(Tf);

    // ---- load all 97 reg-resident cells (c = kb*8+stI; st = w*8+stI, kb = c>>3) ----
    f32x4 tfa[NA];
#pragma unroll
    for (int c = 0; c < NA; ++c) {
        const int kb = c >> 3, stI = c & 7;
        tfa[c] = *reinterpret_cast<const f32x4*>(
            TfC + ((size_t)((w * 8 + stI) * 16 + kb) << 10) + lane * 16);
    }
    f32x4 tfv[NV];
#pragma unroll
    for (int c = NA; c < NA + NV; ++c) {
        const int kb = c >> 3, stI = c & 7;
        tfv[c - NA] = *reinterpret_cast<const f32x4*>(
            TfC + ((size_t)((w * 8 + stI) * 16 + kb) << 10) + lane * 16);
    }
#pragma unroll
    for (int c = 0; c < NA; ++c) asm volatile("" : "+a"(tfa[c]));   // pin to AGPRs
#pragma unroll
    for (int c = 0; c < NV; ++c) asm volatile("" : "+v"(tfv[c]));   // pin to arch VGPRs

    // ---- stage 31 LDS-resident cells (c = 97..127) ----
#pragma unroll
    for (int c = NA + NV; c < 128; ++c) {
        const int kb = c >> 3, stI = c & 7;
        short8 v = *reinterpret_cast<const short8*>(
            TfC + ((size_t)((w * 8 + stI) * 16 + kb) << 10) + lane * 16);
        *reinterpret_cast<short8*>(&Tlds[w][(c - NA - NV) * 1024 + lane * 16]) = v;
    }

    // ---- t = 0: ap0 = Eexp[sym0]*pexp; write A(0) frags; q partials ----
    {
        int symr[4];
#pragma unroll
        for (int r = 0; r < 4; ++r) symr[r] = batch[(size_t)(b0 + hi * 4 + r) * TB];
        float p[4] = {0.f, 0.f, 0.f, 0.f};
#pragma unroll
        for (int stI = 0; stI < 8; ++stI) {
            int s = w * 128 + stI * 16 + lo;
            float pe = pexp[s];
            const int kbp = w * 4 + (stI >> 1);
            const int hip = (stI & 1) * 2 + (lo >> 3);
#pragma unroll
            for (int r = 0; r < 4; ++r) {
                float a = expET[(size_t)symr[r] * NS + s] * pe;
                p[r] += a;
                *reinterpret_cast<unsigned short*>(
                    &Alds[0][kbp * 1024 + (hip * 16 + hi * 4 + r) * 16 + (lo & 7) * 2]) = bf_bits(a);
            }
        }
#pragma unroll
        for (int off = 1; off < 16; off <<= 1)
#pragma unroll
            for (int r = 0; r < 4; ++r) p[r] += __shfl_xor(p[r], off);
        if (lo == 0)
#pragma unroll
            for (int r = 0; r < 4; ++r) qred[0][hi * 4 + r][w] = p[r];
    }
    __syncthreads();

    float nrm = 0.f;   // meaningful in wave 0 (lane L tracks batch L&15)

    // ---- main scan: iteration t consumes A(t-1)/qred(t-1), produces A(t)/qred(t) ----
    for (int t = 1; t < TB; ++t) {
        const int pr = (t - 1) & 1, pw = t & 1;

        // q(t-1) redundantly per thread; wave0 writes out
        f32x4 q4 = *reinterpret_cast<const f32x4*>(&qred[pr][lane & 15][0]);
        float qv = (q4[0] + q4[1]) + (q4[2] + q4[3]);
        float qil = 1.0f / qv;
        if (w == 0) {
            nrm += __logf(qv);
            if (lane < 16) out[(size_t)(b0 + lane) * TB + (t - 1)] = nrm;
        }
        float qi[4];
#pragma unroll
        for (int r = 0; r < 4; ++r) qi[r] = __shfl(qil, hi * 4 + r);

        int symr[4];
#pragma unroll
        for (int r = 0; r < 4; ++r) symr[r] = batch[(size_t)(b0 + hi * 4 + r) * TB + t];

        // GEMM: P_raw[b, s] = sum_k A(t-1)[b,k] * T[s,k] -- all operands CU-resident
        f32x4 acc[8] = {};
        const char* Ab = &Alds[pr][0];
#pragma unroll
        for (int kb = 0; kb < 16; ++kb) {
            short8 af = *reinterpret_cast<const short8*>(Ab + kb * 1024 + lane * 16);
#pragma unroll
            for (int stI = 0; stI < 8; ++stI) {
                const int c = kb * 8 + stI;
                short8 bf;
                if (c < NA) bf = __builtin_bit_cast(short8, tfa[c]);
                else if (c < NA + NV) bf = __builtin_bit_cast(short8, tfv[c - NA]);
                else bf = *reinterpret_cast<const short8*>(
                         &Tlds[w][(c - NA - NV) * 1024 + lane * 16]);
                acc[stI] = __builtin_amdgcn_mfma_f32_16x16x32_bf16(af, bf, acc[stI], 0, 0, 0);
            }
        }

        // epilogue: ap = acc * Eexp * qi; write A(t) frags; q partials
        float p[4] = {0.f, 0.f, 0.f, 0.f};
#pragma unroll
        for (int stI = 0; stI < 8; ++stI) {
            const int kbp = w * 4 + (stI >> 1);
            const int hip = (stI & 1) * 2 + (lo >> 3);
            const int s = w * 128 + stI * 16 + lo;
#pragma unroll
            for (int r = 0; r < 4; ++r) {
                float a = acc[stI][r] * expET[(size_t)symr[r] * NS + s] * qi[r];
                p[r] += a;
                *reinterpret_cast<unsigned short*>(
                    &Alds[pw][kbp * 1024 + (hip * 16 + hi * 4 + r) * 16 + (lo & 7) * 2]) = bf_bits(a);
            }
        }
#pragma unroll
        for (int off = 1; off < 16; off <<= 1)
#pragma unroll
            for (int r = 0; r < 4; ++r) p[r] += __shfl_xor(p[r], off);
        if (lo == 0)
#pragma unroll
            for (int r = 0; r < 4; ++r) qred[pw][hi * 4 + r][w] = p[r];
        __syncthreads();   // the only barrier per step
    }

    // ---- final column t = 255 from qred[1] ----
    if (w == 0) {
        f32x4 q4 = *reinterpret_cast<const f32x4*>(&qred[1][lane & 15][0]);
        float qv = (q4[0] + q4[1]) + (q4[2] + q4[3]);
        nrm += __logf(qv);
        if (lane < 16) out[(size_t)(b0 + lane) * TB + 255] = nrm;
    }
}

extern "C" void kernel_launch(void* const* d_in, const int* in_sizes, int n_in,
                              void* d_out, int out_size, void* d_ws, size_t ws_size,
                              hipStream_t stream) {
    const int* batch = (const int*)d_in[0];
    const float* unE = (const float*)d_in[1];
    const float* unT = (const float*)d_in[2];
    const float* unP = (const float*)d_in[3];
    float* outp = (float*)d_out;

    char* ws = (char*)d_ws;
    float* expET = (float*)(ws + OFF_EEXP);
    float* pexp = (float*)(ws + OFF_PEXP);
    __hip_bfloat16* Tfrag = (__hip_bfloat16*)(ws + OFF_TFRAG);

    k_emission<<<NS, 64, 0, stream>>>(unE, expET);
    k_transition<<<NS, 64, 0, stream>>>(unT, Tfrag);
    k_priors<<<1, 64, 0, stream>>>(unP, pexp);
    k_forward<<<NWG, 256, 0, stream>>>(batch, expET, Tfrag, pexp, outp);
}

// Round 11
// 1063.963 us; speedup vs baseline: 1.4393x; 1.4393x over previous
//
#include <hip/hip_runtime.h>
#include <hip/hip_bf16.h>

#define NS 512     // states
#define MS 256     // symbols
#define TB 256     // sequence length
#define NWG 16     // workgroups = batch groups
#define BPG 16     // batches per group
#define NLDSC 15   // LDS T cells per wave (stL2, kb 0..14)

// workspace byte offsets
#define OFF_EEXP  0u          // f32 [256 sym][512 state] = 512KB
#define OFF_PEXP  524288u     // f32 [512]
#define OFF_TFRAG 526336u     // bf16 fragment-major [32 st][16 kb][64 lane][8] = 512KB

typedef __attribute__((ext_vector_type(8))) short short8;
typedef __attribute__((ext_vector_type(4))) float f32x4;

__device__ __forceinline__ unsigned short bf_bits(float f) {
    __hip_bfloat16 h = __float2bfloat16(f);
    unsigned short u; __builtin_memcpy(&u, &h, 2); return u;
}

__global__ void k_emission(const float* __restrict__ E, float* __restrict__ expET) {
    int n = blockIdx.x;
    int lane = threadIdx.x;
    const float* row = E + (size_t)n * MS;
    float v[4]; float mx = -1e30f;
#pragma unroll
    for (int j = 0; j < 4; ++j) { v[j] = row[lane + 64 * j]; mx = fmaxf(mx, v[j]); }
#pragma unroll
    for (int off = 1; off < 64; off <<= 1) mx = fmaxf(mx, __shfl_xor(mx, off));
    float s = 0.f;
#pragma unroll
    for (int j = 0; j < 4; ++j) s += __expf(v[j] - mx);
#pragma unroll
    for (int off = 1; off < 64; off <<= 1) s += __shfl_xor(s, off);
    float lse = mx + __logf(s);
#pragma unroll
    for (int j = 0; j < 4; ++j)
        expET[(size_t)(lane + 64 * j) * NS + n] = __expf(v[j] - lse);
}

// T fragments, MFMA-lane-major: cell (st,kb) holds T[state=st*16+li][k=kb*32+hk*8+j]
// at byte ((st*16+kb)<<10) + (hk*16+li)*16 + j*2.  Column-softmax over i (dim 0).
__global__ void k_transition(const float* __restrict__ U, __hip_bfloat16* __restrict__ Tf) {
    int k = blockIdx.x;
    int lane = threadIdx.x;
    float v[8]; float mx = -1e30f;
#pragma unroll
    for (int j = 0; j < 8; ++j) { v[j] = U[(size_t)(lane + 64 * j) * NS + k]; mx = fmaxf(mx, v[j]); }
#pragma unroll
    for (int off = 1; off < 64; off <<= 1) mx = fmaxf(mx, __shfl_xor(mx, off));
    float s = 0.f;
#pragma unroll
    for (int j = 0; j < 8; ++j) s += __expf(v[j] - mx);
#pragma unroll
    for (int off = 1; off < 64; off <<= 1) s += __shfl_xor(s, off);
    float lse = mx + __logf(s);
    int kb = k >> 5, hk = (k >> 3) & 3, jj = k & 7;
#pragma unroll
    for (int j = 0; j < 8; ++j) {
        int i = lane + 64 * j;
        int st = i >> 4, li = i & 15;
        size_t byte = ((size_t)(st * 16 + kb) << 10) + (unsigned)(hk * 16 + li) * 16 + jj * 2;
        *reinterpret_cast<unsigned short*>(reinterpret_cast<char*>(Tf) + byte) =
            bf_bits(__expf(v[j] - lse));
    }
}

__global__ void k_priors(const float* __restrict__ U, float* __restrict__ pexp) {
    int lane = threadIdx.x;
    float v[8]; float mx = -1e30f;
#pragma unroll
    for (int j = 0; j < 8; ++j) { v[j] = U[lane + 64 * j]; mx = fmaxf(mx, v[j]); }
#pragma unroll
    for (int off = 1; off < 64; off <<= 1) mx = fmaxf(mx, __shfl_xor(mx, off));
    float s = 0.f;
#pragma unroll
    for (int j = 0; j < 8; ++j) s += __expf(v[j] - mx);
#pragma unroll
    for (int off = 1; off < 64; off <<= 1) s += __shfl_xor(s, off);
    float lse = mx + __logf(s);
#pragma unroll
    for (int j = 0; j < 8; ++j) pexp[lane + 64 * j] = __expf(v[j] - lse);
}

// 16 WGs x 512 threads (8 waves, 2/SIMD for latency hiding; 256 unified regs/wave).
// Wave w owns states [w*64,(w+1)*64) = 64 T-cells (st = w*4+stL, kb 0..15):
//   stL 0,1        -> 32 cells pinned in AGPRs ("+a", 128 regs)
//   stL 2, kb<15   -> 15 cells in LDS (120KB)
//   stL 3 (16) + stL2/kb15 (1) -> streamed from L2 per step, depth-8 rolling ring:
//       slots kb 0..7 prefetched BEFORE the previous barrier; in-loop reload at
//       kb serves kb+8. alpha double-buffered in LDS; deferred normalization
// (rowsum(P_raw(t)) = q(t-1)); one barrier/step; out[b,t] = running sum log q.
__launch_bounds__(512, 2)
__global__ void k_forward(const int* __restrict__ batch, const float* __restrict__ expET,
                          const __hip_bfloat16* __restrict__ Tf,
                          const float* __restrict__ pexp,
                          float* __restrict__ out) {
    __shared__ __align__(16) char Alds[2][16 * 1024];     // 32KB: A frags per kb
    __shared__ __align__(16) char Tlds[8][NLDSC * 1024];  // 120KB
    __shared__ __align__(16) float qred[2][BPG][8];       // 1KB

    const int tid = threadIdx.x;
    const int lane = tid & 63;
    const int w = tid >> 6;       // wave 0..7 -> states [w*64,(w+1)*64)
    const int hi = lane >> 4;
    const int lo = lane & 15;
    const int g = blockIdx.x;
    const int b0 = g * BPG;
    const char* TfC = reinterpret_cast<const char*>(Tf);

#define CELLP(st, kb) (TfC + ((size_t)((st) * 16 + (kb)) << 10) + lane * 16)

    // ---- 32 AGPR-pinned cells: stL 0,1 all kb ----
    f32x4 tfa[32];
#pragma unroll
    for (int kb = 0; kb < 16; ++kb) {
        tfa[kb * 2 + 0] = *reinterpret_cast<const f32x4*>(CELLP(w * 4 + 0, kb));
        tfa[kb * 2 + 1] = *reinterpret_cast<const f32x4*>(CELLP(w * 4 + 1, kb));
    }
#pragma unroll
    for (int c = 0; c < 32; ++c) asm volatile("" : "+a"(tfa[c]));

    // ---- 15 LDS cells: stL2, kb 0..14 ----
#pragma unroll
    for (int kb = 0; kb < NLDSC; ++kb)
        *reinterpret_cast<short8*>(&Tlds[w][kb * 1024 + lane * 16]) =
            *reinterpret_cast<const short8*>(CELLP(w * 4 + 2, kb));

    // ---- streaming ring init: stL3 kb 0..7; xreg = stL2 kb15 ----
    f32x4 ring[8];
#pragma unroll
    for (int i = 0; i < 8; ++i) ring[i] = *reinterpret_cast<const f32x4*>(CELLP(w * 4 + 3, i));
    f32x4 xreg = *reinterpret_cast<const f32x4*>(CELLP(w * 4 + 2, 15));

    // ---- t = 0: ap0 = Eexp[sym0]*pexp; write A(0) frags; q partials ----
    {
        int symr[4];
#pragma unroll
        for (int r = 0; r < 4; ++r) symr[r] = batch[(size_t)(b0 + hi * 4 + r) * TB];
        float p[4] = {0.f, 0.f, 0.f, 0.f};
#pragma unroll
        for (int stL = 0; stL < 4; ++stL) {
            int s = w * 64 + stL * 16 + lo;
            float pe = pexp[s];
            const int kbp = w * 2 + (stL >> 1);
            const int hip = (stL & 1) * 2 + (lo >> 3);
#pragma unroll
            for (int r = 0; r < 4; ++r) {
                float a = expET[(size_t)symr[r] * NS + s] * pe;
                p[r] += a;
                *reinterpret_cast<unsigned short*>(
                    &Alds[0][kbp * 1024 + (hip * 16 + hi * 4 + r) * 16 + (lo & 7) * 2]) = bf_bits(a);
            }
        }
#pragma unroll
        for (int off = 1; off < 16; off <<= 1)
#pragma unroll
            for (int r = 0; r < 4; ++r) p[r] += __shfl_xor(p[r], off);
        if (lo == 0)
#pragma unroll
            for (int r = 0; r < 4; ++r) qred[0][hi * 4 + r][w] = p[r];
    }
    __syncthreads();

    float nrm = 0.f;   // wave 0: lane L tracks batch L&15

    // ---- main scan ----
    for (int t = 1; t < TB; ++t) {
        const int pr = (t - 1) & 1, pw = t & 1;

        // emission loads first (independent -> hide under q path)
        int symr[4];
#pragma unroll
        for (int r = 0; r < 4; ++r) symr[r] = batch[(size_t)(b0 + hi * 4 + r) * TB + t];
        float em[4][4];
#pragma unroll
        for (int stL = 0; stL < 4; ++stL)
#pragma unroll
            for (int r = 0; r < 4; ++r)
                em[stL][r] = expET[(size_t)symr[r] * NS + w * 64 + stL * 16 + lo];

        // q(t-1) redundantly per thread; wave0 writes out
        f32x4 qa = *reinterpret_cast<const f32x4*>(&qred[pr][lane & 15][0]);
        f32x4 qb = *reinterpret_cast<const f32x4*>(&qred[pr][lane & 15][4]);
        float qv = ((qa[0] + qa[1]) + (qa[2] + qa[3])) + ((qb[0] + qb[1]) + (qb[2] + qb[3]));
        float qil = 1.0f / qv;
        if (w == 0) {
            nrm += __logf(qv);
            if (lane < 16) out[(size_t)(b0 + lane) * TB + (t - 1)] = nrm;
        }
        float qi[4];
#pragma unroll
        for (int r = 0; r < 4; ++r) qi[r] = __shfl(qil, hi * 4 + r);
        float fac[4][4];
#pragma unroll
        for (int stL = 0; stL < 4; ++stL)
#pragma unroll
            for (int r = 0; r < 4; ++r) fac[stL][r] = em[stL][r] * qi[r];

        // GEMM: all B-operands CU-resident or ring-prefetched
        f32x4 acc[4] = {};
        const char* Ab = &Alds[pr][0];
#pragma unroll
        for (int kb = 0; kb < 16; ++kb) {
            short8 af = *reinterpret_cast<const short8*>(Ab + kb * 1024 + lane * 16);
            acc[0] = __builtin_amdgcn_mfma_f32_16x16x32_bf16(
                af, __builtin_bit_cast(short8, tfa[kb * 2 + 0]), acc[0], 0, 0, 0);
            acc[1] = __builtin_amdgcn_mfma_f32_16x16x32_bf16(
                af, __builtin_bit_cast(short8, tfa[kb * 2 + 1]), acc[1], 0, 0, 0);
            short8 b2 = (kb < NLDSC)
                ? *reinterpret_cast<const short8*>(&Tlds[w][kb * 1024 + lane * 16])
                : __builtin_bit_cast(short8, xreg);
            acc[2] = __builtin_amdgcn_mfma_f32_16x16x32_bf16(af, b2, acc[2], 0, 0, 0);
            acc[3] = __builtin_amdgcn_mfma_f32_16x16x32_bf16(
                af, __builtin_bit_cast(short8, ring[kb & 7]), acc[3], 0, 0, 0);
            if (kb < 8)   // reload slot for use at kb+8 (latency covered by 8 kb-blocks)
                ring[kb] = *reinterpret_cast<const f32x4*>(CELLP(w * 4 + 3, kb + 8));
        }

        // prefetch next step's ring slots 0..7 + xreg NOW (hidden under epilogue+barrier+q)
#pragma unroll
        for (int i = 0; i < 8; ++i) ring[i] = *reinterpret_cast<const f32x4*>(CELLP(w * 4 + 3, i));
        xreg = *reinterpret_cast<const f32x4*>(CELLP(w * 4 + 2, 15));

        // epilogue: ap = acc * fac; write A(t) frags; q partials
        float p[4] = {0.f, 0.f, 0.f, 0.f};
#pragma unroll
        for (int stL = 0; stL < 4; ++stL) {
            const int kbp = w * 2 + (stL >> 1);
            const int hip = (stL & 1) * 2 + (lo >> 3);
#pragma unroll
            for (int r = 0; r < 4; ++r) {
                float a = acc[stL][r] * fac[stL][r];
                p[r] += a;
                *reinterpret_cast<unsigned short*>(
                    &Alds[pw][kbp * 1024 + (hip * 16 + hi * 4 + r) * 16 + (lo & 7) * 2]) = bf_bits(a);
            }
        }
#pragma unroll
        for (int off = 1; off < 16; off <<= 1)
#pragma unroll
            for (int r = 0; r < 4; ++r) p[r] += __shfl_xor(p[r], off);
        if (lo == 0)
#pragma unroll
            for (int r = 0; r < 4; ++r) qred[pw][hi * 4 + r][w] = p[r];
        __syncthreads();   // the only barrier per step
    }

    // ---- final column t = 255 from qred[1] ----
    if (w == 0) {
        f32x4 qa = *reinterpret_cast<const f32x4*>(&qred[1][lane & 15][0]);
        f32x4 qb = *reinterpret_cast<const f32x4*>(&qred[1][lane & 15][4]);
        float qv = ((qa[0] + qa[1]) + (qa[2] + qa[3])) + ((qb[0] + qb[1]) + (qb[2] + qb[3]));
        nrm += __logf(qv);
        if (lane < 16) out[(size_t)(b0 + lane) * TB + 255] = nrm;
    }
#undef CELLP
}

extern "C" void kernel_launch(void* const* d_in, const int* in_sizes, int n_in,
                              void* d_out, int out_size, void* d_ws, size_t ws_size,
                              hipStream_t stream) {
    const int* batch = (const int*)d_in[0];
    const float* unE = (const float*)d_in[1];
    const float* unT = (const float*)d_in[2];
    const float* unP = (const float*)d_in[3];
    float* outp = (float*)d_out;

    char* ws = (char*)d_ws;
    float* expET = (float*)(ws + OFF_EEXP);
    float* pexp = (float*)(ws + OFF_PEXP);
    __hip_bfloat16* Tfrag = (__hip_bfloat16*)(ws + OFF_TFRAG);

    k_emission<<<NS, 64, 0, stream>>>(unE, expET);
    k_transition<<<NS, 64, 0, stream>>>(unT, Tfrag);
    k_priors<<<1, 64, 0, stream>>>(unP, pexp);
    k_forward<<<NWG, 512, 0, stream>>>(batch, expET, Tfrag, pexp, outp);
}